// Round 8
// baseline (406.631 us; speedup 1.0000x reference)
//
#include <hip/hip_runtime.h>
#include <hip/hip_bf16.h>

// ---------------- problem constants ----------------
// x: [B=8, N1=4, S=64, L=8192], PATCH=128 -> Lp=64, P=128, F=256, Lout=62
// out: [8,4,64,62,1] fp32

typedef _Float16 fp16_t;
typedef _Float16 fp16x8 __attribute__((ext_vector_type(8)));
typedef __fp16 pkh2 __attribute__((ext_vector_type(2)));   // cvt_pkrtz result type
typedef float f32x4 __attribute__((ext_vector_type(4)));

// ws float-word offsets
constexpr int WOFF_CNT   = 0;     // 16 uints
constexpr int WOFF_STRAT = 16;    // 8 ints
constexpr int WOFF_CONST = 32;    // 1 float
constexpr int WOFF_VF    = 64;    // 256 floats
constexpr int WOFF_VB    = 320;   // 256 floats
constexpr int WOFF_NORM  = 1024;                // 8*64*1024 floats
constexpr int WOFF_W1T   = WOFF_NORM + 524288;  // f16 [2][4][256][32]
constexpr int WOFF_CWT   = WOFF_W1T + 32768;    // f16 [2][24][256][32]

constexpr int HSTRIDE = 528;          // 264 f16 per row (256 + 8 pad)
constexpr int HBUF    = 66 * HSTRIDE; // 34848 B per s-half

__device__ __forceinline__ float silu_f(float v) {
    return v / (1.0f + __expf(-v));
}

// ---------------- decide stage (unchanged, verified) ----------------
__global__ __launch_bounds__(256) void norm_kernel(const float* __restrict__ c,
                                                   float* __restrict__ wsf) {
    const int bs = blockIdx.x;
    const int tid = threadIdx.x;
    unsigned int* cnts = (unsigned int*)wsf + WOFF_CNT;
    if (bs == 0 && tid < 16) cnts[tid] = 0u;

    const float* row = c + (size_t)bs * 1024;
    float4 v = ((const float4*)row)[tid];
    float sum = v.x + v.y + v.z + v.w;
    float sq  = v.x*v.x + v.y*v.y + v.z*v.z + v.w*v.w;
    #pragma unroll
    for (int off = 32; off > 0; off >>= 1) {
        sum += __shfl_down(sum, off);
        sq  += __shfl_down(sq, off);
    }
    __shared__ float ls[8];
    __shared__ float stats[2];
    const int w = tid >> 6;
    if ((tid & 63) == 0) { ls[w] = sum; ls[4 + w] = sq; }
    __syncthreads();
    if (tid == 0) {
        float S = ls[0] + ls[1] + ls[2] + ls[3];
        float Q = ls[4] + ls[5] + ls[6] + ls[7];
        float mean = S * (1.0f / 1024.0f);
        float var  = (Q - 1024.0f * mean * mean) * (1.0f / 1023.0f);
        stats[0] = mean;
        stats[1] = 1.0f / sqrtf(var);
    }
    __syncthreads();
    const float mean = stats[0], inv = stats[1];
    float4 o;
    o.x = (v.x - mean) * inv; o.y = (v.y - mean) * inv;
    o.z = (v.z - mean) * inv; o.w = (v.w - mean) * inv;
    ((float4*)(wsf + WOFF_NORM + (size_t)bs * 1024))[tid] = o;
}

__global__ __launch_bounds__(256) void rowcount_kernel(float* __restrict__ wsf) {
    const int bs = blockIdx.x;
    const int b = bs >> 6, s = bs & 63;
    const int tid = threadIdx.x;
    unsigned int* cnts = (unsigned int*)wsf + WOFF_CNT;
    const float* nb = wsf + WOFF_NORM + (size_t)b * 65536;

    __shared__ __align__(16) float rowv[1024];
    *(float4*)&rowv[tid * 4] = *(const float4*)&nb[s * 1024 + tid * 4];
    __syncthreads();

    const int t = tid >> 2, part = tid & 3;
    const float4* src  = (const float4*)(nb + t * 1024 + part * 256);
    const float4* mine = (const float4*)(rowv + part * 256);
    float acc = 0.0f;
    #pragma unroll 8
    for (int i = 0; i < 64; ++i) {
        float4 a = mine[i];
        float4 bb = src[i];
        acc += a.x * bb.x + a.y * bb.y + a.z * bb.z + a.w * bb.w;
    }
    acc += __shfl_down(acc, 2);
    acc += __shfl_down(acc, 1);
    const float corrv = acc * (1.0f / 1024.0f);
    const bool valid = (part == 0) && (t != s);
    unsigned long long mthr = __ballot(valid && (corrv > 0.6f));
    unsigned long long mpos = __ballot(valid && (corrv > 0.0f));
    if ((tid & 63) == 0) {
        atomicAdd(&cnts[b],     (unsigned int)__popcll(mthr));
        atomicAdd(&cnts[8 + b], (unsigned int)__popcll(mpos));
    }
}

// ---------------- parallel pack: 64 blocks (unchanged, verified) ----------------
__global__ __launch_bounds__(256) void pack_kernel(
    const float* __restrict__ W2f, const float* __restrict__ b2f,
    const float* __restrict__ W2b, const float* __restrict__ b2b,
    const float* __restrict__ Wr,  const float* __restrict__ br,
    const float* __restrict__ W1f, const float* __restrict__ W1b,
    const float* __restrict__ Cwf, const float* __restrict__ Cwb,
    float* __restrict__ wsf) {
    const int bid = blockIdx.x;
    const int tid = threadIdx.x;

    if (bid < 48) {
        const int d = bid / 24, ks = bid % 24;
        const float* Cw = d ? Cwb : Cwf;
        fp16_t* cwt = (fp16_t*)(wsf + WOFF_CWT) + d * 196608;
        const int base = ks * 32;
        const int k = base >> 8, i0 = base & 255;
        fp16x8 v[4];
        #pragma unroll
        for (int j = 0; j < 4; ++j)
            #pragma unroll
            for (int e = 0; e < 8; ++e)
                v[j][e] = (fp16_t)Cw[(tid * 256 + i0 + j * 8 + e) * 3 + k];
        fp16x8* dst = (fp16x8*)(cwt + (ks * 256 + tid) * 32);
        dst[0] = v[0]; dst[1] = v[1]; dst[2] = v[2]; dst[3] = v[3];
    } else if (bid < 56) {
        const int sl = bid - 48;
        const int d = sl >> 2, ks = sl & 3;
        const float* W1 = d ? W1b : W1f;
        fp16_t* w1t = (fp16_t*)(wsf + WOFF_W1T) + d * 32768;
        fp16x8 v[4];
        #pragma unroll
        for (int j = 0; j < 4; ++j)
            #pragma unroll
            for (int e = 0; e < 8; ++e)
                v[j][e] = (fp16_t)W1[(ks * 32 + j * 8 + e) * 256 + tid];
        fp16x8* dst = (fp16x8*)(w1t + (ks * 256 + tid) * 32);
        dst[0] = v[0]; dst[1] = v[1]; dst[2] = v[2]; dst[3] = v[3];
    } else {
        const int vb = bid - 56;
        const int d = vb >> 2, q = vb & 3;
        const int w = tid >> 6, lane = tid & 63;
        const float* W2 = d ? W2b : W2f;
        float4 wr4 = ((const float4*)Wr)[lane];
        for (int it = 0; it < 16; ++it) {
            int row = q * 64 + w * 16 + it;
            float4 a = ((const float4*)(W2 + row * 256))[lane];
            float p = a.x * wr4.x + a.y * wr4.y + a.z * wr4.z + a.w * wr4.w;
            #pragma unroll
            for (int off = 32; off > 0; off >>= 1) p += __shfl_down(p, off);
            if (lane == 0) wsf[(d ? WOFF_VB : WOFF_VF) + row] = p;
        }
        if (bid == 56 && tid == 0) {
            const unsigned int* cnts = (const unsigned int*)wsf + WOFF_CNT;
            int* strat = (int*)wsf + WOFF_STRAT;
            float cc = 0.0f;
            for (int g = 0; g < 256; ++g) cc += (b2f[g] + b2b[g]) * Wr[g];
            wsf[WOFF_CONST] = cc + br[0];
            for (int bb = 0; bb < 8; ++bb) {
                unsigned int ct = cnts[bb], cp = cnts[8 + bb];
                unsigned int denom = cp < 1u ? 1u : cp;
                float ratio = (cp > 0u) ? ((float)ct / (float)denom) : 0.0f;
                strat[bb] = (ratio >= 0.4f) ? 1 : 0;
            }
        }
    }
}

// ---------------- fused main: 2 s per block, 8 waves, 32 cols/wave ----------------
// grid 1024 = (b, n, sp); 8 waves; wave w owns output cols [32w, 32w+32).
// launch_bounds(512,3): VGPR cap 170 -- R7's (512,4) capped at 64 and spilled
// (89MB scratch writes). Per-wave live state ~130-160 regs.
__global__ __launch_bounds__(512, 3) void fused_main(
    const float* __restrict__ x,
    const float* __restrict__ b1f, const float* __restrict__ Cbf,
    const float* __restrict__ b1b, const float* __restrict__ Cbb,
    const float* __restrict__ wsf,
    float* __restrict__ out) {
    __shared__ __align__(16) char hball[2 * HBUF];  // two h buffers, rows padded to 528B
    __shared__ float red[128];

    char* hb0 = hball;
    char* hb1 = hball + HBUF;

    const int tid  = threadIdx.x;
    const int w    = tid >> 6;       // 0..7
    const int lane = tid & 63;
    const int l15  = lane & 15;
    const int l4   = lane >> 4;
    const int wc   = w * 32;         // wave col base

    const int mb = blockIdx.x;
    const int b  = mb >> 7;
    const int n  = (mb >> 5) & 3;
    const int sp = mb & 31;
    const int s0 = sp * 2, s1 = s0 + 1;
    const size_t bn = (size_t)(b * 4 + n);

    const int strat = ((const int*)wsf)[WOFF_STRAT + b];

    if (tid < 128) red[tid] = 0.0f;
    // zero pad rows 64,65 of both buffers (conv tail reads them)
    for (int i = tid; i < 528; i += 512) {
        if (i < 264) ((float*)(hb0 + 64 * HSTRIDE))[i] = 0.0f;
        else         ((float*)(hb1 + 64 * HSTRIDE))[i - 264] = 0.0f;
    }

    const char* w1base = (const char*)(wsf + WOFF_W1T);
    const char* cwbase = (const char*)(wsf + WOFF_CWT);

    for (int dir = 0; dir < 2; ++dir) {
        const float* b1 = dir ? b1b : b1f;
        const float* cb = dir ? Cbb : Cbf;
        const char* w1sl = w1base + dir * 65536;
        const char* cwsl = cwbase + dir * 393216;

        // per-t tok row base pointers (N-tiles: t 0..3 -> s0, 4..7 -> s1)
        const float* xbase[8];
        #pragma unroll
        for (int t = 0; t < 8; ++t) {
            int sv = (t < 4) ? s0 : s1;
            int sg = dir ? (63 - sv) : sv;
            int lp = (t & 3) * 16 + l15;
            int r1i = strat ? lp : sg;
            int r2i = strat ? sg : lp;
            xbase[t] = x + ((bn * 64 + r1i) * 8192 + (size_t)r2i * 128 + l4 * 8);
        }

        // ---------- GEMM1 (swapped): h[l][f] = silu(tok@W1 + b1) ----------
        f32x4 acc1[2][8];
        #pragma unroll
        for (int i = 0; i < 2; ++i)
            #pragma unroll
            for (int j = 0; j < 8; ++j)
                acc1[i][j] = (f32x4){0.f, 0.f, 0.f, 0.f};

        #pragma unroll
        for (int ks = 0; ks < 4; ++ks) {
            fp16x8 wa[2];   // A = W1 frags (M = f, wave's 32 cols)
            #pragma unroll
            for (int mt = 0; mt < 2; ++mt)
                wa[mt] = *(const fp16x8*)(w1sl
                    + (ks * 256 + wc + mt * 16 + l15) * 64 + l4 * 16);
            fp16x8 tb[8];   // B = tok frags (N = l, all 128 rows)
            #pragma unroll
            for (int t = 0; t < 8; ++t) {
                const float* p = xbase[t] + ks * 32;
                float4 p0 = *(const float4*)p;
                float4 p1 = *(const float4*)(p + 4);
                union { fp16x8 v; pkh2 h2[4]; } u;
                u.h2[0] = __builtin_amdgcn_cvt_pkrtz(p0.x, p0.y);
                u.h2[1] = __builtin_amdgcn_cvt_pkrtz(p0.z, p0.w);
                u.h2[2] = __builtin_amdgcn_cvt_pkrtz(p1.x, p1.y);
                u.h2[3] = __builtin_amdgcn_cvt_pkrtz(p1.z, p1.w);
                tb[t] = u.v;
            }
            #pragma unroll
            for (int mt = 0; mt < 2; ++mt)
                #pragma unroll
                for (int t = 0; t < 8; ++t)
                    acc1[mt][t] = __builtin_amdgcn_mfma_f32_16x16x32_f16(
                        wa[mt], tb[t], acc1[mt][t], 0, 0, 0);
        }

        // bias values for this lane's f rows
        float b1r[2][4];
        #pragma unroll
        for (int mt = 0; mt < 2; ++mt)
            #pragma unroll
            for (int q = 0; q < 4; ++q)
                b1r[mt][q] = b1[wc + mt * 16 + l4 * 4 + q];

        __syncthreads();  // prev dir's conv reads of h done
        #pragma unroll
        for (int t = 0; t < 8; ++t) {
            char* hbt = (t < 4) ? hb0 : hb1;
            int l = (t & 3) * 16 + l15;
            char* dst = hbt + l * HSTRIDE + (wc + l4 * 4) * 2;
            #pragma unroll
            for (int mt = 0; mt < 2; ++mt) {
                f32x4 a = acc1[mt][t];
                union { pkh2 h2[2]; uint2 u; } pk;
                pk.h2[0] = __builtin_amdgcn_cvt_pkrtz(
                    silu_f(a[0] + b1r[mt][0]), silu_f(a[1] + b1r[mt][1]));
                pk.h2[1] = __builtin_amdgcn_cvt_pkrtz(
                    silu_f(a[2] + b1r[mt][2]), silu_f(a[3] + b1r[mt][3]));
                *(uint2*)(dst + mt * 32) = pk.u;
            }
        }
        __syncthreads();

        // ---------- conv GEMM: M=128 (both s-halves), K=768, 24 slices ----------
        f32x4 acc2[8][2];
        #pragma unroll
        for (int i = 0; i < 8; ++i)
            #pragma unroll
            for (int j = 0; j < 2; ++j)
                acc2[i][j] = (f32x4){0.f, 0.f, 0.f, 0.f};

        const char* cw_w = cwsl + (size_t)(wc + l15) * 64 + l4 * 16;
        fp16x8 bq[2];
        #pragma unroll
        for (int t = 0; t < 2; ++t)
            bq[t] = *(const fp16x8*)(cw_w + t * 1024);

        for (int ks = 0; ks < 24; ++ks) {
            fp16x8 bnx[2];
            if (ks < 23) {
                #pragma unroll
                for (int t = 0; t < 2; ++t)
                    bnx[t] = *(const fp16x8*)(cw_w + (ks + 1) * 16384 + t * 1024);
            }
            const int base = (l15 + (ks >> 3)) * HSTRIDE + (ks & 7) * 64 + l4 * 16;
            const char* h0p = hb0 + base;
            const char* h1p = hb1 + base;
            fp16x8 af[8];
            #pragma unroll
            for (int mt = 0; mt < 4; ++mt) {
                af[mt]     = *(const fp16x8*)(h0p + mt * (16 * HSTRIDE));
                af[mt + 4] = *(const fp16x8*)(h1p + mt * (16 * HSTRIDE));
            }
            #pragma unroll
            for (int t = 0; t < 2; ++t)
                #pragma unroll
                for (int mt = 0; mt < 8; ++mt)
                    acc2[mt][t] = __builtin_amdgcn_mfma_f32_16x16x32_f16(
                        af[mt], bq[t], acc2[mt][t], 0, 0, 0);
            #pragma unroll
            for (int t = 0; t < 2; ++t) bq[t] = bnx[t];
        }

        // epilogue: silu(conv + cb) * v, reduce over o -> red
        float cbv[2], vv[2];
        #pragma unroll
        for (int t = 0; t < 2; ++t) {
            int col = wc + t * 16 + l15;
            cbv[t] = cb[col];
            vv[t]  = wsf[(dir ? WOFF_VB : WOFF_VF) + col];
        }
        #pragma unroll
        for (int mt = 0; mt < 8; ++mt) {
            #pragma unroll
            for (int q = 0; q < 4; ++q) {
                float v0 = 0.f;
                #pragma unroll
                for (int t = 0; t < 2; ++t)
                    v0 += silu_f(acc2[mt][t][q] + cbv[t]) * vv[t];
                v0 += __shfl_xor(v0, 1);
                v0 += __shfl_xor(v0, 2);
                v0 += __shfl_xor(v0, 4);
                v0 += __shfl_xor(v0, 8);
                if (l15 == 0) {
                    int idx = (mt >> 2) * 64 + (mt & 3) * 16 + l4 * 4 + q;
                    atomicAdd(&red[idx], v0);
                }
            }
        }
    }

    __syncthreads();
    const float constv = wsf[WOFF_CONST];
    if (tid < 62)
        out[(bn * 64 + s0) * 62 + tid] = red[tid] + constv;
    if (tid >= 64 && tid < 126)
        out[(bn * 64 + s1) * 62 + (tid - 64)] = red[tid] + constv;
}

extern "C" void kernel_launch(void* const* d_in, const int* in_sizes, int n_in,
                              void* d_out, int out_size, void* d_ws, size_t ws_size,
                              hipStream_t stream) {
    (void)in_sizes; (void)n_in; (void)out_size; (void)ws_size;
    const float* x    = (const float*)d_in[0];
    const float* corr = (const float*)d_in[1];
    const float* W1f  = (const float*)d_in[2];
    const float* b1f  = (const float*)d_in[3];
    const float* Cwf  = (const float*)d_in[4];
    const float* Cbf  = (const float*)d_in[5];
    const float* W2f  = (const float*)d_in[6];
    const float* b2f  = (const float*)d_in[7];
    const float* W1b  = (const float*)d_in[8];
    const float* b1b  = (const float*)d_in[9];
    const float* Cwb  = (const float*)d_in[10];
    const float* Cbb  = (const float*)d_in[11];
    const float* W2b  = (const float*)d_in[12];
    const float* b2b  = (const float*)d_in[13];
    const float* Wr   = (const float*)d_in[14];
    const float* br   = (const float*)d_in[15];
    float* out = (float*)d_out;
    float* wsf = (float*)d_ws;

    norm_kernel<<<512, 256, 0, stream>>>(corr, wsf);
    rowcount_kernel<<<512, 256, 0, stream>>>(wsf);
    pack_kernel<<<64, 256, 0, stream>>>(W2f, b2f, W2b, b2b, Wr, br,
                                        W1f, W1b, Cwf, Cwb, wsf);
    fused_main<<<1024, 512, 0, stream>>>(x, b1f, Cbf, b1b, Cbb, wsf, out);
}

// Round 9
// 270.048 us; speedup vs baseline: 1.5058x; 1.5058x over previous
//
#include <hip/hip_runtime.h>
#include <hip/hip_bf16.h>

// ---------------- problem constants ----------------
// x: [B=8, N1=4, S=64, L=8192], PATCH=128 -> Lp=64, P=128, F=256, Lout=62
// out: [8,4,64,62,1] fp32

typedef _Float16 fp16_t;
typedef _Float16 fp16x8 __attribute__((ext_vector_type(8)));
typedef __fp16 pkh2 __attribute__((ext_vector_type(2)));   // cvt_pkrtz result type
typedef float f32x4 __attribute__((ext_vector_type(4)));

// ws float-word offsets
constexpr int WOFF_CNT   = 0;     // 16 uints
constexpr int WOFF_STRAT = 16;    // 8 ints
constexpr int WOFF_CONST = 32;    // 1 float
constexpr int WOFF_VF    = 64;    // 256 floats
constexpr int WOFF_VB    = 320;   // 256 floats
constexpr int WOFF_W1T   = 1024;                // f16 [2][4][256][32]
constexpr int WOFF_CWT   = WOFF_W1T + 32768;    // f16 [2][24][256][32]

constexpr int HBUF = 66 * 512;    // 33792 B per s-half, rows 512B XOR-swizzled

__device__ __forceinline__ float silu_f(float v) {
    return v / (1.0f + __expf(-v));
}

// ---------------- decide stage: raw-space corr counting ----------------
// grid 512 (= b*64+s): counts from RAW correlations.
// corr_st > c  <=>  dot - 1024*ms*mt > c*1024*sigs*sigt  (norm algebra folded in)
__global__ __launch_bounds__(256) void rowcount_kernel(const float* __restrict__ c,
                                                       float* __restrict__ wsf) {
    const int bs = blockIdx.x;
    const int b = bs >> 6, s = bs & 63;
    const int tid = threadIdx.x;
    unsigned int* cnts = (unsigned int*)wsf + WOFF_CNT;
    const float* cb = c + (size_t)b * 65536;

    __shared__ __align__(16) float rowv[1024];
    __shared__ float ms_sh, ss_sh;
    *(float4*)&rowv[tid * 4] = *(const float4*)&cb[s * 1024 + tid * 4];
    __syncthreads();

    const int t = tid >> 2, part = tid & 3;
    const float4* src  = (const float4*)(cb + t * 1024 + part * 256);
    const float4* mine = (const float4*)(rowv + part * 256);
    float dot = 0.0f, sum = 0.0f, sq = 0.0f;
    #pragma unroll 8
    for (int i = 0; i < 64; ++i) {
        float4 a = mine[i];
        float4 bb = src[i];
        dot += a.x * bb.x + a.y * bb.y + a.z * bb.z + a.w * bb.w;
        sum += bb.x + bb.y + bb.z + bb.w;
        sq  += bb.x * bb.x + bb.y * bb.y + bb.z * bb.z + bb.w * bb.w;
    }
    dot += __shfl_down(dot, 2); dot += __shfl_down(dot, 1);
    sum += __shfl_down(sum, 2); sum += __shfl_down(sum, 1);
    sq  += __shfl_down(sq, 2);  sq  += __shfl_down(sq, 1);

    float mt = 0.0f, st = 0.0f;
    if (part == 0) {
        mt = sum * (1.0f / 1024.0f);
        st = sqrtf(fmaxf((sq - 1024.0f * mt * mt) * (1.0f / 1023.0f), 0.0f));
        if (t == s) { ms_sh = mt; ss_sh = st; }
    }
    __syncthreads();
    const float ms = ms_sh, ss = ss_sh;

    const bool valid = (part == 0) && (t != s);
    const float ctr = dot - 1024.0f * ms * mt;                 // 1024*cov
    // corr = ctr / (1023*ss*st) / ... careful: corr = ctr/(1024*ss*st)*(1024/1023)?
    // norm_i=(c-m)/sig with sig^2=(sq-N m^2)/(N-1); corr=sum(ns*nt)/N = ctr/(N*ss*st)
    unsigned long long mthr = __ballot(valid && (ctr > 0.6f * 1024.0f * ss * st));
    unsigned long long mpos = __ballot(valid && (ctr > 0.0f));
    if ((tid & 63) == 0) {
        atomicAdd(&cnts[b],     (unsigned int)__popcll(mthr));
        atomicAdd(&cnts[8 + b], (unsigned int)__popcll(mpos));
    }
}

// ---------------- parallel pack: 64 blocks (unchanged, verified) ----------------
__global__ __launch_bounds__(256) void pack_kernel(
    const float* __restrict__ W2f, const float* __restrict__ b2f,
    const float* __restrict__ W2b, const float* __restrict__ b2b,
    const float* __restrict__ Wr,  const float* __restrict__ br,
    const float* __restrict__ W1f, const float* __restrict__ W1b,
    const float* __restrict__ Cwf, const float* __restrict__ Cwb,
    float* __restrict__ wsf) {
    const int bid = blockIdx.x;
    const int tid = threadIdx.x;

    if (bid < 48) {
        const int d = bid / 24, ks = bid % 24;
        const float* Cw = d ? Cwb : Cwf;
        fp16_t* cwt = (fp16_t*)(wsf + WOFF_CWT) + d * 196608;
        const int base = ks * 32;
        const int k = base >> 8, i0 = base & 255;
        fp16x8 v[4];
        #pragma unroll
        for (int j = 0; j < 4; ++j)
            #pragma unroll
            for (int e = 0; e < 8; ++e)
                v[j][e] = (fp16_t)Cw[(tid * 256 + i0 + j * 8 + e) * 3 + k];
        fp16x8* dst = (fp16x8*)(cwt + (ks * 256 + tid) * 32);
        dst[0] = v[0]; dst[1] = v[1]; dst[2] = v[2]; dst[3] = v[3];
    } else if (bid < 56) {
        const int sl = bid - 48;
        const int d = sl >> 2, ks = sl & 3;
        const float* W1 = d ? W1b : W1f;
        fp16_t* w1t = (fp16_t*)(wsf + WOFF_W1T) + d * 32768;
        fp16x8 v[4];
        #pragma unroll
        for (int j = 0; j < 4; ++j)
            #pragma unroll
            for (int e = 0; e < 8; ++e)
                v[j][e] = (fp16_t)W1[(ks * 32 + j * 8 + e) * 256 + tid];
        fp16x8* dst = (fp16x8*)(w1t + (ks * 256 + tid) * 32);
        dst[0] = v[0]; dst[1] = v[1]; dst[2] = v[2]; dst[3] = v[3];
    } else {
        const int vb = bid - 56;
        const int d = vb >> 2, q = vb & 3;
        const int w = tid >> 6, lane = tid & 63;
        const float* W2 = d ? W2b : W2f;
        float4 wr4 = ((const float4*)Wr)[lane];
        for (int it = 0; it < 16; ++it) {
            int row = q * 64 + w * 16 + it;
            float4 a = ((const float4*)(W2 + row * 256))[lane];
            float p = a.x * wr4.x + a.y * wr4.y + a.z * wr4.z + a.w * wr4.w;
            #pragma unroll
            for (int off = 32; off > 0; off >>= 1) p += __shfl_down(p, off);
            if (lane == 0) wsf[(d ? WOFF_VB : WOFF_VF) + row] = p;
        }
        if (bid == 56 && tid == 0) {
            const unsigned int* cnts = (const unsigned int*)wsf + WOFF_CNT;
            int* strat = (int*)wsf + WOFF_STRAT;
            float cc = 0.0f;
            for (int g = 0; g < 256; ++g) cc += (b2f[g] + b2b[g]) * Wr[g];
            wsf[WOFF_CONST] = cc + br[0];
            for (int bb = 0; bb < 8; ++bb) {
                unsigned int ct = cnts[bb], cp = cnts[8 + bb];
                unsigned int denom = cp < 1u ? 1u : cp;
                float ratio = (cp > 0u) ? ((float)ct / (float)denom) : 0.0f;
                strat[bb] = (ratio >= 0.4f) ? 1 : 0;
            }
        }
    }
}

// ---------------- fused main: R6 structure + XOR-swizzled h (512B rows) -------
// grid 1024 = (b, n, sp); 4 waves; wave w owns output cols [64w, 64w+64).
// h element (l, f): byte = (l*512 + f*2) ^ ((l&7)<<4) within its s-half buffer.
__global__ __launch_bounds__(256, 2) void fused_main(
    const float* __restrict__ x,
    const float* __restrict__ b1f, const float* __restrict__ Cbf,
    const float* __restrict__ b1b, const float* __restrict__ Cbb,
    const float* __restrict__ wsf,
    float* __restrict__ out) {
    __shared__ __align__(16) char hball[2 * HBUF];
    __shared__ float red[128];

    char* hb0 = hball;
    char* hb1 = hball + HBUF;

    const int tid  = threadIdx.x;
    const int w    = tid >> 6;       // 0..3
    const int lane = tid & 63;
    const int l15  = lane & 15;
    const int l4   = lane >> 4;
    const int wc   = w * 64;

    const int mb = blockIdx.x;
    const int b  = mb >> 7;
    const int n  = (mb >> 5) & 3;
    const int sp = mb & 31;
    const int s0 = sp * 2, s1 = s0 + 1;
    const size_t bn = (size_t)(b * 4 + n);

    const int strat = ((const int*)wsf)[WOFF_STRAT + b];

    if (tid < 128) red[tid] = 0.0f;
    // zero pad rows 64,65 of both buffers (1024 B each; swizzle permutes within rows)
    ((unsigned int*)(hb0 + 64 * 512))[tid] = 0u;
    ((unsigned int*)(hb1 + 64 * 512))[tid] = 0u;

    const char* w1base = (const char*)(wsf + WOFF_W1T);
    const char* cwbase = (const char*)(wsf + WOFF_CWT);

    for (int dir = 0; dir < 2; ++dir) {
        const float* b1 = dir ? b1b : b1f;
        const float* cb = dir ? Cbb : Cbf;
        const char* w1sl = w1base + dir * 65536;
        const char* cwsl = cwbase + dir * 393216;

        // per-t tok row base pointers (N-tiles: t 0..3 -> s0, 4..7 -> s1)
        const float* xbase[8];
        #pragma unroll
        for (int t = 0; t < 8; ++t) {
            int sv = (t < 4) ? s0 : s1;
            int sg = dir ? (63 - sv) : sv;
            int lp = (t & 3) * 16 + l15;
            int r1i = strat ? lp : sg;
            int r2i = strat ? sg : lp;
            xbase[t] = x + ((bn * 64 + r1i) * 8192 + (size_t)r2i * 128 + l4 * 8);
        }

        // ---------- GEMM1 (swapped): h[l][f] = silu(tok@W1 + b1) ----------
        f32x4 acc1[4][8];
        #pragma unroll
        for (int i = 0; i < 4; ++i)
            #pragma unroll
            for (int j = 0; j < 8; ++j)
                acc1[i][j] = (f32x4){0.f, 0.f, 0.f, 0.f};

        #pragma unroll
        for (int ks = 0; ks < 4; ++ks) {
            fp16x8 wa[4];   // A = W1 frags (M = f)
            #pragma unroll
            for (int mt = 0; mt < 4; ++mt)
                wa[mt] = *(const fp16x8*)(w1sl
                    + (ks * 256 + wc + mt * 16 + l15) * 64 + l4 * 16);
            fp16x8 tb[8];   // B = tok frags (N = l)
            #pragma unroll
            for (int t = 0; t < 8; ++t) {
                const float* p = xbase[t] + ks * 32;
                float4 p0 = *(const float4*)p;
                float4 p1 = *(const float4*)(p + 4);
                union { fp16x8 v; pkh2 h2[4]; } u;
                u.h2[0] = __builtin_amdgcn_cvt_pkrtz(p0.x, p0.y);
                u.h2[1] = __builtin_amdgcn_cvt_pkrtz(p0.z, p0.w);
                u.h2[2] = __builtin_amdgcn_cvt_pkrtz(p1.x, p1.y);
                u.h2[3] = __builtin_amdgcn_cvt_pkrtz(p1.z, p1.w);
                tb[t] = u.v;
            }
            #pragma unroll
            for (int mt = 0; mt < 4; ++mt)
                #pragma unroll
                for (int t = 0; t < 8; ++t)
                    acc1[mt][t] = __builtin_amdgcn_mfma_f32_16x16x32_f16(
                        wa[mt], tb[t], acc1[mt][t], 0, 0, 0);
        }

        // bias values for this lane's f rows
        float b1r[4][4];
        #pragma unroll
        for (int mt = 0; mt < 4; ++mt)
            #pragma unroll
            for (int q = 0; q < 4; ++q)
                b1r[mt][q] = b1[wc + mt * 16 + l4 * 4 + q];

        __syncthreads();  // prev dir's conv reads of h done
        #pragma unroll
        for (int t = 0; t < 8; ++t) {
            char* hbt = (t < 4) ? hb0 : hb1;
            int l = (t & 3) * 16 + l15;
            int rowoff = l * 512;
            int sw = (l & 7) << 4;
            #pragma unroll
            for (int mt = 0; mt < 4; ++mt) {
                f32x4 a = acc1[mt][t];
                union { pkh2 h2[2]; uint2 u; } pk;
                pk.h2[0] = __builtin_amdgcn_cvt_pkrtz(
                    silu_f(a[0] + b1r[mt][0]), silu_f(a[1] + b1r[mt][1]));
                pk.h2[1] = __builtin_amdgcn_cvt_pkrtz(
                    silu_f(a[2] + b1r[mt][2]), silu_f(a[3] + b1r[mt][3]));
                int byte = (rowoff + (wc + mt * 16 + l4 * 4) * 2) ^ sw;
                *(uint2*)(hbt + byte) = pk.u;
            }
        }
        __syncthreads();

        // ---------- conv GEMM: M=128 (both s-halves), K=768, 24 slices ----------
        f32x4 acc2[8][4];
        #pragma unroll
        for (int i = 0; i < 8; ++i)
            #pragma unroll
            for (int j = 0; j < 4; ++j)
                acc2[i][j] = (f32x4){0.f, 0.f, 0.f, 0.f};

        const char* cw_w = cwsl + (size_t)(wc + l15) * 64 + l4 * 16;
        fp16x8 bq[4];
        #pragma unroll
        for (int t = 0; t < 4; ++t)
            bq[t] = *(const fp16x8*)(cw_w + t * 1024);

        for (int ks = 0; ks < 24; ++ks) {
            fp16x8 bnx[4];
            if (ks < 23) {
                #pragma unroll
                for (int t = 0; t < 4; ++t)
                    bnx[t] = *(const fp16x8*)(cw_w + (ks + 1) * 16384 + t * 1024);
            }
            const int brow = l15 + (ks >> 3);
            const int base = (brow * 512 + (ks & 7) * 64 + l4 * 16)
                             ^ ((brow & 7) << 4);
            const char* h0p = hb0 + base;
            const char* h1p = hb1 + base;
            fp16x8 af[8];
            #pragma unroll
            for (int mt = 0; mt < 4; ++mt) {
                af[mt]     = *(const fp16x8*)(h0p + mt * 8192);
                af[mt + 4] = *(const fp16x8*)(h1p + mt * 8192);
            }
            #pragma unroll
            for (int t = 0; t < 4; ++t)
                #pragma unroll
                for (int mt = 0; mt < 8; ++mt)
                    acc2[mt][t] = __builtin_amdgcn_mfma_f32_16x16x32_f16(
                        af[mt], bq[t], acc2[mt][t], 0, 0, 0);
            #pragma unroll
            for (int t = 0; t < 4; ++t) bq[t] = bnx[t];
        }

        // epilogue: silu(conv + cb) * v, reduce over o -> red
        float cbv[4], vv[4];
        #pragma unroll
        for (int t = 0; t < 4; ++t) {
            int col = wc + t * 16 + l15;
            cbv[t] = cb[col];
            vv[t]  = wsf[(dir ? WOFF_VB : WOFF_VF) + col];
        }
        #pragma unroll
        for (int mt = 0; mt < 8; ++mt) {
            #pragma unroll
            for (int q = 0; q < 4; ++q) {
                float v0 = 0.f;
                #pragma unroll
                for (int t = 0; t < 4; ++t)
                    v0 += silu_f(acc2[mt][t][q] + cbv[t]) * vv[t];
                v0 += __shfl_xor(v0, 1);
                v0 += __shfl_xor(v0, 2);
                v0 += __shfl_xor(v0, 4);
                v0 += __shfl_xor(v0, 8);
                if (l15 == 0) {
                    int idx = (mt >> 2) * 64 + (mt & 3) * 16 + l4 * 4 + q;
                    atomicAdd(&red[idx], v0);
                }
            }
        }
    }

    __syncthreads();
    const float constv = wsf[WOFF_CONST];
    if (tid < 62)
        out[(bn * 64 + s0) * 62 + tid] = red[tid] + constv;
    if (tid >= 64 && tid < 126)
        out[(bn * 64 + s1) * 62 + (tid - 64)] = red[tid] + constv;
}

extern "C" void kernel_launch(void* const* d_in, const int* in_sizes, int n_in,
                              void* d_out, int out_size, void* d_ws, size_t ws_size,
                              hipStream_t stream) {
    (void)in_sizes; (void)n_in; (void)out_size; (void)ws_size;
    const float* x    = (const float*)d_in[0];
    const float* corr = (const float*)d_in[1];
    const float* W1f  = (const float*)d_in[2];
    const float* b1f  = (const float*)d_in[3];
    const float* Cwf  = (const float*)d_in[4];
    const float* Cbf  = (const float*)d_in[5];
    const float* W2f  = (const float*)d_in[6];
    const float* b2f  = (const float*)d_in[7];
    const float* W1b  = (const float*)d_in[8];
    const float* b1b  = (const float*)d_in[9];
    const float* Cwb  = (const float*)d_in[10];
    const float* Cbb  = (const float*)d_in[11];
    const float* W2b  = (const float*)d_in[12];
    const float* b2b  = (const float*)d_in[13];
    const float* Wr   = (const float*)d_in[14];
    const float* br   = (const float*)d_in[15];
    float* out = (float*)d_out;
    float* wsf = (float*)d_ws;

    hipMemsetAsync(wsf + WOFF_CNT, 0, 16 * sizeof(unsigned int), stream);
    rowcount_kernel<<<512, 256, 0, stream>>>(corr, wsf);
    pack_kernel<<<64, 256, 0, stream>>>(W2f, b2f, W2b, b2b, Wr, br,
                                        W1f, W1b, Cwf, Cwb, wsf);
    fused_main<<<1024, 256, 0, stream>>>(x, b1f, Cbf, b1b, Cbb, wsf, out);
}